// Round 2
// baseline (22907.249 us; speedup 1.0000x reference)
//
#include <hip/hip_runtime.h>
#include <math.h>

// ---------------- problem dims ----------------
#define VV 32000
#define HH 512
#define G3 1536   // 3*HH
#define TI 128    // encoder length
#define TO 64     // max decode length
#define NB 5      // beam width
#define NEGF (-1000000000.0f)

// ---------------- grid config ----------------
#define NWG 256
#define NTHR 256
#define BGRP 8
#define WPG (NWG / BGRP)

struct Params {
  const int* seq;
  const int* sosp;
  const float *emb, *eWi, *eWh, *ebi, *ebh;
  const float *dWi, *dWh, *dbi, *dbh;
  const float *Wc, *bc, *Wout, *bout;
  unsigned* bar;
  int *cur_tok, *toks, *pars, *ptop_i;
  float *gi0, *eout, *h0b, *h1b, *dch, *ctx, *cc, *ptop_v, *psum, *scores;
  float* out;
};

__device__ __forceinline__ float wredf(float v) {
#pragma unroll
  for (int o = 32; o; o >>= 1) v += __shfl_xor(v, o, 64);
  return v;  // all lanes hold identical (order-symmetric) result
}

// Two-level monotonic-counter grid barrier. bar must be zeroed per launch.
__device__ __forceinline__ void gbar(unsigned* bar, int ph) {
  __syncthreads();
  if (threadIdx.x == 0) {
    __threadfence();
    unsigned* gc = bar + (blockIdx.x / WPG) * 32;  // padded group counters
    unsigned* gl = bar + BGRP * 32;                // global counter
    unsigned* rl = bar + BGRP * 32 + 32;           // release word
    unsigned v = atomicAdd(gc, 1u) + 1u;
    if (v == (unsigned)(WPG * ph)) {
      unsigned w = atomicAdd(gl, 1u) + 1u;
      if (w == (unsigned)(BGRP * ph))
        __hip_atomic_store(rl, (unsigned)ph, __ATOMIC_RELEASE, __HIP_MEMORY_SCOPE_AGENT);
    }
    while (__hip_atomic_load(rl, __ATOMIC_ACQUIRE, __HIP_MEMORY_SCOPE_AGENT) < (unsigned)ph)
      __builtin_amdgcn_s_sleep(2);
    __threadfence();
  }
  __syncthreads();
}

// one GRU layer of the decoder across the whole grid.
// layer 0: x = emb[cur_tok[b]]; layer 1: x = dch[ob][0][b].
// h input gathered through pars[t-1] (identity at t==0).
__device__ void dec_gru(const Params& p, float* sm, int layer, int t, int ib, int ob) {
  const int wg = blockIdx.x, tid = threadIdx.x;
  const int lane = tid & 63, wv = tid >> 6;
  float* sx = sm;                 // [NB][HH]
  float* sh = sm + NB * HH;       // [NB][HH]
  float* fres = sm + 2 * NB * HH; // [12][NB]
  for (int i = tid; i < NB * HH; i += NTHR) {
    int b = i / HH, u = i - b * HH;
    const float* xs = (layer == 0) ? (p.emb + (size_t)p.cur_tok[b] * HH)
                                   : (p.dch + ((size_t)(ob * 2 + 0) * NB + b) * HH);
    sx[i] = xs[u];
    int pb = (t == 0) ? b : p.pars[(t - 1) * NB + b];
    sh[i] = p.dch[((size_t)(ib * 2 + layer) * NB + pb) * HH + u];
  }
  __syncthreads();
  const float* Wi = p.dWi + (size_t)layer * G3 * HH;
  const float* Wh = p.dWh + (size_t)layer * G3 * HH;
  for (int f = wv; f < 12; f += 4) {
    int ul = f / 6, fm = f % 6;
    int g = fm % 3;
    bool isWh = fm >= 3;
    int u = wg * 2 + ul;
    const float* W = (isWh ? Wh : Wi) + (size_t)(g * HH + u) * HH;
    const float* vecb = isWh ? sh : sx;
    float w0[8];
#pragma unroll
    for (int j = 0; j < 8; j++) w0[j] = W[j * 64 + lane];
    float a0 = 0.f, a1 = 0.f, a2 = 0.f, a3 = 0.f, a4 = 0.f;
#pragma unroll
    for (int j = 0; j < 8; j++) {
      float wj = w0[j];
      int o = j * 64 + lane;
      a0 += wj * vecb[0 * HH + o];
      a1 += wj * vecb[1 * HH + o];
      a2 += wj * vecb[2 * HH + o];
      a3 += wj * vecb[3 * HH + o];
      a4 += wj * vecb[4 * HH + o];
    }
    float r0 = wredf(a0), r1 = wredf(a1), r2 = wredf(a2), r3 = wredf(a3), r4 = wredf(a4);
    if (lane == 0) {
      fres[f * NB + 0] = r0; fres[f * NB + 1] = r1; fres[f * NB + 2] = r2;
      fres[f * NB + 3] = r3; fres[f * NB + 4] = r4;
    }
  }
  __syncthreads();
  if (tid < 2 * NB) {
    int ul = tid / NB, b = tid - ul * NB;
    int u = wg * 2 + ul;
    const float* bi = p.dbi + layer * G3;
    const float* bh = p.dbh + layer * G3;
    float ir = fres[(ul * 6 + 0) * NB + b] + bi[u];
    float iz = fres[(ul * 6 + 1) * NB + b] + bi[HH + u];
    float inn = fres[(ul * 6 + 2) * NB + b] + bi[2 * HH + u];
    float hr = fres[(ul * 6 + 3) * NB + b] + bh[u];
    float hz = fres[(ul * 6 + 4) * NB + b] + bh[HH + u];
    float hn = fres[(ul * 6 + 5) * NB + b] + bh[2 * HH + u];
    float hp = sh[b * HH + u];
    float r = 1.f / (1.f + expf(-(ir + hr)));
    float z = 1.f / (1.f + expf(-(iz + hz)));
    float n = tanhf(inn + r * hn);
    p.dch[((size_t)(ob * 2 + layer) * NB + b) * HH + u] = (1.f - z) * n + z * hp;
  }
}

__global__ void __launch_bounds__(NTHR) bsd_kernel(Params p) {
  const int wg = blockIdx.x, tid = threadIdx.x;
  const int lane = tid & 63, wv = tid >> 6;
  __shared__ float sm[5248];
  int ph = 0;

  // ========== E0: gi0[t][row] = emb[seq[t]] . Wi0[row] + bi0[row]; zero h state ==========
  {
    // FULL zero of the double-buffered hidden states (2*HH each!).
    // Previous bug: `tid < HH` with 256 threads zeroed only [0,256) -> replays
    // started from the prior call's leftover encoder state (tripwire failure).
    if (wg == 0) {
      for (int i = tid; i < 2 * HH; i += NTHR) { p.h0b[i] = 0.f; p.h1b[i] = 0.f; }
    }
    for (int lr = wv; lr < 6; lr += 4) {
      int row = wg * 6 + lr;
      const float* W = p.eWi + (size_t)row * HH;
      float w0[8];
#pragma unroll
      for (int j = 0; j < 8; j++) w0[j] = W[j * 64 + lane];
      float bi = p.ebi[row];
      for (int t = 0; t < TI; t++) {
        const float* x = p.emb + (size_t)p.seq[t] * HH;
        float s = 0.f;
#pragma unroll
        for (int j = 0; j < 8; j++) s += w0[j] * x[j * 64 + lane];
        s = wredf(s);
        if (lane == 0) p.gi0[(size_t)t * G3 + row] = s + bi;
      }
    }
  }
  gbar(p.bar, ++ph);

  // ========== E1: 129 iterations, L0 step T overlapped with L1 step T-1 ==========
  for (int T = 0; T <= TI; T++) {
    const int sIn = T & 1, sOut = sIn ^ 1;
    if (wv < 2) {
      if (T < TI) {
        int u = wg * 2 + wv;
        const float* hprev = p.h0b + sIn * HH;
        float hv[8];
#pragma unroll
        for (int j = 0; j < 8; j++) hv[j] = hprev[j * 64 + lane];
        float g[3];
#pragma unroll
        for (int gg = 0; gg < 3; gg++) {
          const float* W = p.eWh + (size_t)(gg * HH + u) * HH;
          float s = 0.f;
#pragma unroll
          for (int j = 0; j < 8; j++) s += W[j * 64 + lane] * hv[j];
          g[gg] = wredf(s);
        }
        if (lane == 0) {
          const float* gr = p.gi0 + (size_t)T * G3;
          float ir = gr[u], iz = gr[HH + u], inn = gr[2 * HH + u];
          float hr = g[0] + p.ebh[u], hz = g[1] + p.ebh[HH + u], hn = g[2] + p.ebh[2 * HH + u];
          float r = 1.f / (1.f + expf(-(ir + hr)));
          float z = 1.f / (1.f + expf(-(iz + hz)));
          float n = tanhf(inn + r * hn);
          p.h0b[sOut * HH + u] = (1.f - z) * n + z * hprev[u];
        }
      }
    } else {
      if (T >= 1) {
        int u = wg * 2 + (wv - 2);
        const float* xsrc = p.h0b + sIn * HH;    // L0 output of step T-1
        const float* hprev = p.h1b + sOut * HH;  // h1 state after step T-2
        float xv[8], hv[8];
#pragma unroll
        for (int j = 0; j < 8; j++) { xv[j] = xsrc[j * 64 + lane]; hv[j] = hprev[j * 64 + lane]; }
        float gi[3], gh[3];
#pragma unroll
        for (int gg = 0; gg < 3; gg++) {
          const float* Wi1 = p.eWi + (size_t)G3 * HH + (size_t)(gg * HH + u) * HH;
          const float* Wh1 = p.eWh + (size_t)G3 * HH + (size_t)(gg * HH + u) * HH;
          float si = 0.f, s2 = 0.f;
#pragma unroll
          for (int j = 0; j < 8; j++) { si += Wi1[j * 64 + lane] * xv[j]; s2 += Wh1[j * 64 + lane] * hv[j]; }
          gi[gg] = wredf(si);
          gh[gg] = wredf(s2);
        }
        if (lane == 0) {
          const float* bi = p.ebi + G3;
          const float* bh = p.ebh + G3;
          float ir = gi[0] + bi[u], iz = gi[1] + bi[HH + u], inn = gi[2] + bi[2 * HH + u];
          float hr = gh[0] + bh[u], hz = gh[1] + bh[HH + u], hn = gh[2] + bh[2 * HH + u];
          float r = 1.f / (1.f + expf(-(ir + hr)));
          float z = 1.f / (1.f + expf(-(iz + hz)));
          float n = tanhf(inn + r * hn);
          float hnew = (1.f - z) * n + z * hprev[u];
          p.h1b[sIn * HH + u] = hnew;
          p.eout[(size_t)(T - 1) * HH + u] = hnew;
        }
      }
    }
    gbar(p.bar, ++ph);
  }

  // ========== D0: broadcast enc_hidden to all beams, init tokens/scores ==========
  {
    for (int i = tid + wg * NTHR; i < 2 * NB * HH; i += NWG * NTHR) {
      int l = i / (NB * HH);
      int rem = i - l * (NB * HH);
      int u = rem % HH;
      p.dch[(size_t)(0 * 2 + l) * NB * HH + rem] = (l == 0) ? p.h0b[u] : p.h1b[u];
    }
    if (wg == 0 && tid < NB) {
      p.cur_tok[tid] = p.sosp[0];
      p.scores[tid] = (tid == 0) ? 0.f : NEGF;
    }
  }
  gbar(p.bar, ++ph);

  // ========== decoder: 64 steps x 6 phases ==========
  for (int t = 0; t < TO; t++) {
    const int ib = t & 1, ob = ib ^ 1;

    // ---- P1: GRU layer 0 ----
    dec_gru(p, sm, 0, t, ib, ob);
    gbar(p.bar, ++ph);

    // ---- P2: GRU layer 1 (produces rnn) ----
    dec_gru(p, sm, 1, t, ib, ob);
    gbar(p.bar, ++ph);

    // ---- P3: attention (one WG per beam) ----
    if (wg < NB) {
      int b = wg;
      float* srnn = sm;        // 512
      float* se = sm + HH;     // 128
      for (int i = tid; i < HH; i += NTHR)
        srnn[i] = p.dch[((size_t)(ob * 2 + 1) * NB + b) * HH + i];
      __syncthreads();
      for (int j = wv; j < TI; j += 4) {
        const float* E = p.eout + (size_t)j * HH;
        float s = 0.f;
#pragma unroll
        for (int k = 0; k < 8; k++) s += srnn[k * 64 + lane] * E[k * 64 + lane];
        s = wredf(s);
        if (lane == 0) se[j] = s;
      }
      __syncthreads();
      if (wv == 0) {
        float v0 = se[lane], v1 = se[64 + lane];
        float mx = fmaxf(v0, v1);
#pragma unroll
        for (int o = 32; o; o >>= 1) mx = fmaxf(mx, __shfl_xor(mx, o, 64));
        float e0 = expf(v0 - mx), e1 = expf(v1 - mx);
        float ss = wredf(e0 + e1);
        se[lane] = e0 / ss;
        se[64 + lane] = e1 / ss;
      }
      __syncthreads();
      for (int u = tid; u < HH; u += NTHR) {
        float s = 0.f;
        for (int j = 0; j < TI; j++) s += se[j] * p.eout[(size_t)j * HH + u];
        p.ctx[b * HH + u] = s;
      }
    }
    gbar(p.bar, ++ph);

    // ---- P4: cc = tanh([rnn,ctx] @ Wc^T + bc) ----
    {
      float* sr = sm;           // rnn [NB][HH]
      float* sc_ = sm + NB * HH; // ctx [NB][HH]
      float* part = sm + 2 * NB * HH; // [4][NB]
      for (int i = tid; i < NB * HH; i += NTHR) {
        int b = i / HH, u = i - b * HH;
        sr[i] = p.dch[((size_t)(ob * 2 + 1) * NB + b) * HH + u];
        sc_[i] = p.ctx[i];
      }
      __syncthreads();
      int ul = wv >> 1, half = wv & 1;
      int u = wg * 2 + ul;
      const float* W = p.Wc + (size_t)u * (2 * HH) + half * HH;
      const float* vec = half ? sc_ : sr;
      float w0[8];
#pragma unroll
      for (int j = 0; j < 8; j++) w0[j] = W[j * 64 + lane];
      float a0 = 0.f, a1 = 0.f, a2 = 0.f, a3 = 0.f, a4 = 0.f;
#pragma unroll
      for (int j = 0; j < 8; j++) {
        float wj = w0[j];
        int o = j * 64 + lane;
        a0 += wj * vec[0 * HH + o];
        a1 += wj * vec[1 * HH + o];
        a2 += wj * vec[2 * HH + o];
        a3 += wj * vec[3 * HH + o];
        a4 += wj * vec[4 * HH + o];
      }
      float r0 = wredf(a0), r1 = wredf(a1), r2 = wredf(a2), r3 = wredf(a3), r4 = wredf(a4);
      if (lane == 0) {
        part[wv * NB + 0] = r0; part[wv * NB + 1] = r1; part[wv * NB + 2] = r2;
        part[wv * NB + 3] = r3; part[wv * NB + 4] = r4;
      }
      __syncthreads();
      if (tid < 2 * NB) {
        int ul2 = tid / NB, b = tid - ul2 * NB;
        int u2 = wg * 2 + ul2;
        float s = part[(ul2 * 2 + 0) * NB + b] + part[(ul2 * 2 + 1) * NB + b] + p.bc[u2];
        p.cc[b * HH + u2] = tanhf(s);
      }
    }
    gbar(p.bar, ++ph);

    // ---- P5: logits chunk (125 vocab rows/WG) + per-beam partial top5 + exp-sum ----
    {
      float* scc = sm;            // [NB][HH]
      float* slg = sm + NB * HH;  // [NB][125]
      for (int i = tid; i < NB * HH; i += NTHR) scc[i] = p.cc[i];
      __syncthreads();
      const int vbase = wg * 125;
      for (int r = wv; r < 125; r += 4) {
        int v = vbase + r;
        const float* W = p.Wout + (size_t)v * HH;
        float w0[8];
#pragma unroll
        for (int j = 0; j < 8; j++) w0[j] = W[j * 64 + lane];
        float a0 = 0.f, a1 = 0.f, a2 = 0.f, a3 = 0.f, a4 = 0.f;
#pragma unroll
        for (int j = 0; j < 8; j++) {
          float wj = w0[j];
          int o = j * 64 + lane;
          a0 += wj * scc[0 * HH + o];
          a1 += wj * scc[1 * HH + o];
          a2 += wj * scc[2 * HH + o];
          a3 += wj * scc[3 * HH + o];
          a4 += wj * scc[4 * HH + o];
        }
        float r0 = wredf(a0), r1 = wredf(a1), r2 = wredf(a2), r3 = wredf(a3), r4 = wredf(a4);
        if (lane == 0) {
          float bo = p.bout[v];
          slg[0 * 125 + r] = r0 + bo;
          slg[1 * 125 + r] = r1 + bo;
          slg[2 * 125 + r] = r2 + bo;
          slg[3 * 125 + r] = r3 + bo;
          slg[4 * 125 + r] = r4 + bo;
        }
      }
      __syncthreads();
      if (wv == 0) {
        for (int b = 0; b < NB; b++) {
          float s0 = (lane < 125) ? expf(slg[b * 125 + lane]) : 0.f;
          float s1 = (lane + 64 < 125) ? expf(slg[b * 125 + lane + 64]) : 0.f;
          float ss = wredf(s0 + s1);
          if (lane == 0) p.psum[wg * NB + b] = ss;
        }
      } else if (wv == 1 && lane < NB) {
        int b = lane;
        float bv[5]; int bidx[5];
#pragma unroll
        for (int k = 0; k < 5; k++) { bv[k] = -INFINITY; bidx[k] = 0x7fffffff; }
        for (int r = 0; r < 125; r++) {
          float v = slg[b * 125 + r];
          if (v > bv[4]) {  // strict >: equal values keep the earlier (lower) index
            int k = 4;
            while (k > 0 && v > bv[k - 1]) { bv[k] = bv[k - 1]; bidx[k] = bidx[k - 1]; k--; }
            bv[k] = v; bidx[k] = vbase + r;
          }
        }
#pragma unroll
        for (int k = 0; k < 5; k++) {
          p.ptop_v[(wg * NB + b) * 5 + k] = bv[k];
          p.ptop_i[(wg * NB + b) * 5 + k] = bidx[k];
        }
      }
    }
    gbar(p.bar, ++ph);

    // ---- P6: merge (WG 0 only): lse, global top5/beam, 25-candidate top5, bookkeeping ----
    if (wg == 0) {
      float* sval = sm;                  // [256][5]
      int* sidx = (int*)(sm + 1280);     // [256][5]
      float* sls = sm + 2560;            // [5]
      float* smv = sm + 2576;            // [5][5]
      int* smi = (int*)(sm + 2608);      // [5][5]
      if (wv == 0) {
        for (int b = 0; b < NB; b++) {
          float q0 = p.psum[(lane + 0) * NB + b];
          float q1 = p.psum[(lane + 64) * NB + b];
          float q2 = p.psum[(lane + 128) * NB + b];
          float q3 = p.psum[(lane + 192) * NB + b];
          float s = wredf((q0 + q1) + (q2 + q3));
          if (lane == 0) sls[b] = logf(s);
        }
      }
      __syncthreads();
      for (int b = 0; b < NB; b++) {
#pragma unroll
        for (int k = 0; k < 5; k++) {
          sval[tid * 5 + k] = p.ptop_v[(tid * NB + b) * 5 + k];
          sidx[tid * 5 + k] = p.ptop_i[(tid * NB + b) * 5 + k];
        }
        __syncthreads();
        for (int n = 128; n >= 1; n >>= 1) {
          if (tid < n) {
            float av[5], bv[5], ov[5];
            int ai[5], bi2[5], oi[5];
#pragma unroll
            for (int k = 0; k < 5; k++) {
              av[k] = sval[tid * 5 + k]; ai[k] = sidx[tid * 5 + k];
              bv[k] = sval[(tid + n) * 5 + k]; bi2[k] = sidx[(tid + n) * 5 + k];
            }
            int i = 0, j = 0;
#pragma unroll
            for (int k = 0; k < 5; k++) {
              bool ta = (av[i] > bv[j]) || (av[i] == bv[j] && ai[i] < bi2[j]);
              if (ta) { ov[k] = av[i]; oi[k] = ai[i]; i++; }
              else { ov[k] = bv[j]; oi[k] = bi2[j]; j++; }
            }
#pragma unroll
            for (int k = 0; k < 5; k++) { sval[tid * 5 + k] = ov[k]; sidx[tid * 5 + k] = oi[k]; }
          }
          __syncthreads();
        }
        if (tid == 0) {
#pragma unroll
          for (int k = 0; k < 5; k++) { smv[b * 5 + k] = sval[k]; smi[b * 5 + k] = sidx[k]; }
        }
        __syncthreads();
      }
      if (tid == 0) {
        float cand[25]; int ctok[25];
        for (int b = 0; b < NB; b++) {
          float sb = p.scores[b], lb = sls[b];
#pragma unroll
          for (int k = 0; k < 5; k++) {
            cand[b * 5 + k] = sb + (smv[b * 5 + k] - lb);
            ctok[b * 5 + k] = smi[b * 5 + k];
          }
        }
        float s5[5]; int f5[5];
#pragma unroll
        for (int k = 0; k < 5; k++) { s5[k] = -INFINITY; f5[k] = 0x7fffffff; }
        for (int f = 0; f < 25; f++) {
          float v = cand[f];
          if (v > s5[4]) {
            int k = 4;
            while (k > 0 && v > s5[k - 1]) { s5[k] = s5[k - 1]; f5[k] = f5[k - 1]; k--; }
            s5[k] = v; f5[k] = f;
          }
        }
        for (int j2 = 0; j2 < 5; j2++) {
          int fl = f5[j2];
          int par = fl / 5;
          int nt = ctok[fl];
          p.pars[t * NB + j2] = par;
          p.toks[t * NB + j2] = nt;
          p.cur_tok[j2] = nt;
        }
        for (int j2 = 0; j2 < 5; j2++) p.scores[j2] = s5[j2];
      }
    }
    gbar(p.bar, ++ph);
  }

  // ========== F: backtrack and write output (seq as float, then score) ==========
  if (wg == 0 && tid == 0) {
    int best = 0;
    float bvv = p.scores[0];
    for (int j = 1; j < NB; j++)
      if (p.scores[j] > bvv) { bvv = p.scores[j]; best = j; }
    int beam = best;
    for (int tt = TO - 1; tt >= 0; tt--) {
      p.out[tt] = (float)p.toks[tt * NB + beam];
      beam = p.pars[tt * NB + beam];
    }
    p.out[TO] = bvv;
  }
}

extern "C" void kernel_launch(void* const* d_in, const int* in_sizes, int n_in,
                              void* d_out, int out_size, void* d_ws, size_t ws_size,
                              hipStream_t stream) {
  (void)in_sizes; (void)n_in; (void)out_size; (void)ws_size;
  Params p;
  p.seq  = (const int*)d_in[0];
  p.sosp = (const int*)d_in[3];
  p.emb  = (const float*)d_in[4];
  p.eWi  = (const float*)d_in[5];
  p.eWh  = (const float*)d_in[6];
  p.ebi  = (const float*)d_in[7];
  p.ebh  = (const float*)d_in[8];
  p.dWi  = (const float*)d_in[9];
  p.dWh  = (const float*)d_in[10];
  p.dbi  = (const float*)d_in[11];
  p.dbh  = (const float*)d_in[12];
  p.Wc   = (const float*)d_in[13];
  p.bc   = (const float*)d_in[14];
  p.Wout = (const float*)d_in[15];
  p.bout = (const float*)d_in[16];

  char* w = (char*)d_ws;
  size_t off = 0;
  auto alloc = [&](size_t words) -> char* {
    char* r = w + off;
    off += words * 4;
    off = (off + 255) & ~(size_t)255;
    return r;
  };
  p.bar     = (unsigned*)alloc(512);          // must stay first (memset below)
  p.cur_tok = (int*)alloc(8);
  p.toks    = (int*)alloc(TO * NB);
  p.pars    = (int*)alloc(TO * NB);
  p.ptop_i  = (int*)alloc(NWG * NB * 5);
  p.gi0     = (float*)alloc((size_t)TI * G3);
  p.eout    = (float*)alloc((size_t)TI * HH);
  p.h0b     = (float*)alloc(2 * HH);
  p.h1b     = (float*)alloc(2 * HH);
  p.dch     = (float*)alloc(2 * 2 * NB * HH);
  p.ctx     = (float*)alloc(NB * HH);
  p.cc      = (float*)alloc(NB * HH);
  p.ptop_v  = (float*)alloc(NWG * NB * 5);
  p.psum    = (float*)alloc(NWG * NB);
  p.scores  = (float*)alloc(8);
  p.out     = (float*)d_out;

  hipMemsetAsync(d_ws, 0, 2048, stream);  // zero barrier counters each call
  void* args[] = { &p };
  hipLaunchCooperativeKernel((void*)bsd_kernel, dim3(NWG), dim3(NTHR), args, 0, stream);
}